// Round 3
// baseline (381.100 us; speedup 1.0000x reference)
//
#include <hip/hip_runtime.h>
#include <stdint.h>

#define NTAG    10
#define SEQ     512
#define BATCH   8192
#define NEG_INF -10000.0f
#define BT10    (BATCH * NTAG)   // 81920: per-timestep dword stride

// ---------------------------------------------------------------------------
// One Viterbi output tag for one batch: 10 candidate adds, exact fmax tree
// (no vcc on the recurrence chain), then first-max index via a descending
// eq-overwrite chain (== jnp.argmax first-occurrence ties; off the fv chain).
// ---------------------------------------------------------------------------
__device__ __forceinline__ void slot10(const float r[10], const float tr[10],
                                       float feat, float& fv_out, uint32_t& bp)
{
    float c[10];
#pragma unroll
    for (int p = 0; p < 10; ++p) c[p] = r[p] + tr[p];

    const float m01 = fmaxf(c[0], c[1]), m23 = fmaxf(c[2], c[3]);
    const float m45 = fmaxf(c[4], c[5]), m67 = fmaxf(c[6], c[7]);
    const float m89 = fmaxf(c[8], c[9]);
    const float m03 = fmaxf(m01, m23), m47 = fmaxf(m45, m67);
    const float vstar = fmaxf(fmaxf(m03, m47), m89);

    fv_out = vstar + feat;                 // recurrence: pure add/max chain

    uint32_t bidx = 9u;                    // at least one candidate matches
#pragma unroll
    for (int p = 8; p >= 0; --p)
        bidx = (c[p] == vstar) ? (uint32_t)p : bidx;   // lowest p wins ties
    bp = bidx;
}

// ---------------------------------------------------------------------------
// Forward Viterbi, quad-DPP exchange. 4 lanes per batch (quad lane q owns
// output tags q, q+4, and 8+q for q<2), fv state = 3 regs/lane. Per step the
// 10 fv values are broadcast with 10 mov_dpp quad_perm broadcasts SHARED by
// all three tag slots -> ~135 instrs per wave-step for 16 batches (8.5
// issues/batch-step vs 41 in the 16-lane version). No LDS, no pads, no
// wasted candidates. 512 blocks x 64 threads = 512 waves at 1/SIMD.
// fp32 adds/max bitwise-identical to the reference; ties = first max.
// ---------------------------------------------------------------------------
__global__ __launch_bounds__(64, 1) void crf_fwd(
    const float* __restrict__ feats, const float* __restrict__ trans,
    float* __restrict__ path_score, int* __restrict__ last_tag,
    uint32_t* __restrict__ bpw)
{
    const int lane = threadIdx.x & 63;
    const int q    = lane & 3;             // quad lane = tag group
    const int grp  = lane >> 2;            // batch within wave (0..15)
    const int b    = blockIdx.x * 16 + grp;   // 512*16 = 8192 exact

    const int nA = q, nB = q + 4;
    const int rowC = (q < 2) ? (8 + q) : 9;   // clamped: lanes 2,3 slot-C dummy

    // transition rows for the owned tags — register-resident
    float trA[10], trB[10], trC[10];
#pragma unroll
    for (int p = 0; p < 10; ++p) {
        trA[p] = trans[nA * NTAG + p];
        trB[p] = trans[nB * NTAG + p];
        trC[p] = trans[rowC * NTAG + p];
    }

    // init: fv[p] = (p==8) ? 0 : -1e4.  A=fv[q], B=fv[q+4], C=fv[8+q]
    float fvA = NEG_INF, fvB = NEG_INF, fvC = (q == 0) ? 0.0f : NEG_INF;

    const float* fpA = feats + b * NTAG + q;          // +0 -> nA, +4 -> nB
    const float* fpC = fpA + ((q < 2) ? 8 : 0);       // clamp keeps in-bounds
    uint32_t* bp_out = bpw + b * NTAG + q;

    // software pipeline: 8 steps (one bp-word period) prefetched ahead
    float fcA[8], fcB[8], fcC[8];
#pragma unroll
    for (int j = 0; j < 8; ++j) {
        fcA[j] = fpA[j * BT10];
        fcB[j] = fpA[j * BT10 + 4];
        fcC[j] = fpC[j * BT10];
    }
    fpA += 8 * BT10; fpC += 8 * BT10;

    for (int w = 0; w < SEQ / 8; ++w) {
        float fnA[8], fnB[8], fnC[8];
        if (w < SEQ / 8 - 1) {
#pragma unroll
            for (int j = 0; j < 8; ++j) {
                fnA[j] = fpA[j * BT10];
                fnB[j] = fpA[j * BT10 + 4];
                fnC[j] = fpC[j * BT10];
            }
            fpA += 8 * BT10; fpC += 8 * BT10;
        } else {
#pragma unroll
            for (int j = 0; j < 8; ++j) { fnA[j] = 0.0f; fnB[j] = 0.0f; fnC[j] = 0.0f; }
        }

        uint32_t baA = 0, baB = 0, baC = 0;
#pragma unroll
        for (int j = 0; j < 8; ++j) {
            const int Ai = __float_as_int(fvA);
            const int Bi = __float_as_int(fvB);
            const int Ci = __float_as_int(fvC);
            // broadcast all 10 fv values once (quad_perm [s,s,s,s] = s*0x55);
            // shared by all three tag slots below
            float r[10];
            r[0] = __int_as_float(__builtin_amdgcn_mov_dpp(Ai, 0x00, 0xF, 0xF, false));
            r[1] = __int_as_float(__builtin_amdgcn_mov_dpp(Ai, 0x55, 0xF, 0xF, false));
            r[2] = __int_as_float(__builtin_amdgcn_mov_dpp(Ai, 0xAA, 0xF, 0xF, false));
            r[3] = __int_as_float(__builtin_amdgcn_mov_dpp(Ai, 0xFF, 0xF, 0xF, false));
            r[4] = __int_as_float(__builtin_amdgcn_mov_dpp(Bi, 0x00, 0xF, 0xF, false));
            r[5] = __int_as_float(__builtin_amdgcn_mov_dpp(Bi, 0x55, 0xF, 0xF, false));
            r[6] = __int_as_float(__builtin_amdgcn_mov_dpp(Bi, 0xAA, 0xF, 0xF, false));
            r[7] = __int_as_float(__builtin_amdgcn_mov_dpp(Bi, 0xFF, 0xF, 0xF, false));
            r[8] = __int_as_float(__builtin_amdgcn_mov_dpp(Ci, 0x00, 0xF, 0xF, false));
            r[9] = __int_as_float(__builtin_amdgcn_mov_dpp(Ci, 0x55, 0xF, 0xF, false));

            uint32_t bpA, bpB, bpC;
            slot10(r, trA, fcA[j], fvA, bpA);   // r[] fixed: overwrite of fv ok
            slot10(r, trB, fcB[j], fvB, bpB);
            slot10(r, trC, fcC[j], fvC, bpC);   // lanes 2,3: dummy, never used
            baA |= bpA << (4 * j);
            baB |= bpB << (4 * j);
            baC |= bpC << (4 * j);
        }
        bp_out[0] = baA;                       // tags q and q+4: all lanes
        bp_out[4] = baB;
        if (q < 2) bp_out[8] = baC;            // tags 8,9: lanes 0,1 only
        bp_out += BT10;
#pragma unroll
        for (int j = 0; j < 8; ++j) { fcA[j] = fnA[j]; fcB[j] = fnB[j]; fcC[j] = fnC[j]; }
    }

    // terminal: term[p] = fv[p] + T[STOP][p]; exact max + first-max index
    {
        const int Ai = __float_as_int(fvA);
        const int Bi = __float_as_int(fvB);
        const int Ci = __float_as_int(fvC);
        float r[10];
        r[0] = __int_as_float(__builtin_amdgcn_mov_dpp(Ai, 0x00, 0xF, 0xF, false));
        r[1] = __int_as_float(__builtin_amdgcn_mov_dpp(Ai, 0x55, 0xF, 0xF, false));
        r[2] = __int_as_float(__builtin_amdgcn_mov_dpp(Ai, 0xAA, 0xF, 0xF, false));
        r[3] = __int_as_float(__builtin_amdgcn_mov_dpp(Ai, 0xFF, 0xF, 0xF, false));
        r[4] = __int_as_float(__builtin_amdgcn_mov_dpp(Bi, 0x00, 0xF, 0xF, false));
        r[5] = __int_as_float(__builtin_amdgcn_mov_dpp(Bi, 0x55, 0xF, 0xF, false));
        r[6] = __int_as_float(__builtin_amdgcn_mov_dpp(Bi, 0xAA, 0xF, 0xF, false));
        r[7] = __int_as_float(__builtin_amdgcn_mov_dpp(Bi, 0xFF, 0xF, 0xF, false));
        r[8] = __int_as_float(__builtin_amdgcn_mov_dpp(Ci, 0x00, 0xF, 0xF, false));
        r[9] = __int_as_float(__builtin_amdgcn_mov_dpp(Ci, 0x55, 0xF, 0xF, false));

        float c[10];
#pragma unroll
        for (int p = 0; p < 10; ++p) c[p] = r[p] + trans[90 + p];
        const float m01 = fmaxf(c[0], c[1]), m23 = fmaxf(c[2], c[3]);
        const float m45 = fmaxf(c[4], c[5]), m67 = fmaxf(c[6], c[7]);
        const float m89 = fmaxf(c[8], c[9]);
        const float m03 = fmaxf(m01, m23), m47 = fmaxf(m45, m67);
        const float vstar = fmaxf(fmaxf(m03, m47), m89);
        uint32_t bt = 9u;
#pragma unroll
        for (int p = 8; p >= 0; --p) bt = (c[p] == vstar) ? (uint32_t)p : bt;

        if (q == 0) { path_score[b] = vstar; last_tag[b] = (int)bt; }
    }
}

// ---------------------------------------------------------------------------
// Pass A: per (chunk c, batch b) compose the 32 per-step backpointer maps in
// registers. Loads coalesced (40 contiguous B/thread) and tag-independent.
// ---------------------------------------------------------------------------
__global__ __launch_bounds__(256) void crf_chunkmap(
    const uint32_t* __restrict__ bpw, uint64_t* __restrict__ cmap)
{
    const int tid = blockIdx.x * 256 + threadIdx.x;   // 131072 = 16 * 8192
    const int b = tid & (BATCH - 1);
    const int c = tid >> 13;

    uint32_t comp[NTAG];
#pragma unroll
    for (int t = 0; t < NTAG; ++t) comp[t] = t;       // identity

    for (int w = 3; w >= 0; --w) {                    // global word c*4+w
        const uint32_t* wp = bpw + (c * 4 + w) * BT10 + b * NTAG;
        const uint64_t q0 = *(const uint64_t*)(wp + 0);
        const uint64_t q1 = *(const uint64_t*)(wp + 2);
        const uint64_t q2 = *(const uint64_t*)(wp + 4);
        const uint64_t q3 = *(const uint64_t*)(wp + 6);
        const uint64_t q4 = *(const uint64_t*)(wp + 8);
        uint32_t wd[10];
        wd[0] = (uint32_t)q0; wd[1] = (uint32_t)(q0 >> 32);
        wd[2] = (uint32_t)q1; wd[3] = (uint32_t)(q1 >> 32);
        wd[4] = (uint32_t)q2; wd[5] = (uint32_t)(q2 >> 32);
        wd[6] = (uint32_t)q3; wd[7] = (uint32_t)(q3 >> 32);
        wd[8] = (uint32_t)q4; wd[9] = (uint32_t)(q4 >> 32);
#pragma unroll
        for (int t = 7; t >= 0; --t) {
            uint32_t lo = 0;
#pragma unroll
            for (int gg = 0; gg < 8; ++gg) lo |= ((wd[gg] >> (4 * t)) & 15u) << (4 * gg);
            const uint32_t hi = ((wd[8] >> (4 * t)) & 15u)
                              | (((wd[9] >> (4 * t)) & 15u) << 4);
            const uint64_t m = ((uint64_t)hi << 32) | lo;
#pragma unroll
            for (int qq = 0; qq < NTAG; ++qq)
                comp[qq] = (uint32_t)((m >> (comp[qq] * 4)) & 15u);
        }
    }
    uint64_t out = 0;
#pragma unroll
    for (int qq = 0; qq < NTAG; ++qq) out |= (uint64_t)comp[qq] << (4 * qq);
    cmap[tid] = out;                                   // tid = c*8192 + b
}

// ---------------------------------------------------------------------------
// Pass B: resolve chunk-entry tags (16 independent loads + register chain).
// ---------------------------------------------------------------------------
__global__ __launch_bounds__(256) void crf_resolve(
    const uint64_t* __restrict__ cmap, const int* __restrict__ last_tag,
    uint8_t* __restrict__ ebuf)
{
    const int b = blockIdx.x * 256 + threadIdx.x;      // 0..8191
    uint64_t cm[16];
#pragma unroll
    for (int c = 0; c < 16; ++c) cm[c] = cmap[c * BATCH + b];
    uint32_t tag = (uint32_t)last_tag[b];
    ebuf[15 * BATCH + b] = (uint8_t)tag;
#pragma unroll
    for (int c = 15; c >= 1; --c) {
        tag = (uint32_t)((cm[c] >> (tag * 4)) & 15u);
        ebuf[(c - 1) * BATCH + b] = (uint8_t)tag;
    }
}

// ---------------------------------------------------------------------------
// Pass C: emit. Re-walk each chunk with the known entry tag; word select by
// tag = cndmask tree (register-space); stores coalesced over b.
// ---------------------------------------------------------------------------
__global__ __launch_bounds__(256) void crf_emit(
    const uint32_t* __restrict__ bpw, const uint8_t* __restrict__ ebuf,
    float* __restrict__ best_path)
{
    const int tid = blockIdx.x * 256 + threadIdx.x;    // 131072
    const int b = tid & (BATCH - 1);
    const int c = tid >> 13;
    uint32_t tag = ebuf[c * BATCH + b];

    for (int w = 3; w >= 0; --w) {
        const uint32_t* wp = bpw + (c * 4 + w) * BT10 + b * NTAG;
        const uint64_t q0 = *(const uint64_t*)(wp + 0);
        const uint64_t q1 = *(const uint64_t*)(wp + 2);
        const uint64_t q2 = *(const uint64_t*)(wp + 4);
        const uint64_t q3 = *(const uint64_t*)(wp + 6);
        const uint64_t q4 = *(const uint64_t*)(wp + 8);
        uint32_t wd[10];
        wd[0] = (uint32_t)q0; wd[1] = (uint32_t)(q0 >> 32);
        wd[2] = (uint32_t)q1; wd[3] = (uint32_t)(q1 >> 32);
        wd[4] = (uint32_t)q2; wd[5] = (uint32_t)(q2 >> 32);
        wd[6] = (uint32_t)q3; wd[7] = (uint32_t)(q3 >> 32);
        wd[8] = (uint32_t)q4; wd[9] = (uint32_t)(q4 >> 32);
#pragma unroll
        for (int t = 7; t >= 0; --t) {
            best_path[(c * 32 + w * 8 + t) * BATCH + b] = (float)tag;  // tag_t
            const uint32_t s0 = (tag & 1) ? wd[1] : wd[0];
            const uint32_t s2 = (tag & 1) ? wd[3] : wd[2];
            const uint32_t s4 = (tag & 1) ? wd[5] : wd[4];
            const uint32_t s6 = (tag & 1) ? wd[7] : wd[6];
            const uint32_t s8 = (tag & 1) ? wd[9] : wd[8];
            const uint32_t t0 = (tag & 2) ? s2 : s0;
            const uint32_t t4 = (tag & 2) ? s6 : s4;
            const uint32_t u0 = (tag & 4) ? t4 : t0;
            const uint32_t sel = (tag & 8) ? s8 : u0;
            tag = (sel >> (4 * t)) & 15u;                              // tag_{t-1}
        }
    }
}

// ---------------------------------------------------------------------------
// d_ws layout (22.2 MB total):
//   [0, 20971520)            bpw  : 64 words x 81920 uint32 (nibble bp)
//   [20971520, +32768)       ltag : 8192 int32
//   [21004288, +1048576)     cmap : 16 x 8192 uint64 (packed chunk maps)
//   [22052864, +131072)      ebuf : 16 x 8192 bytes
// ---------------------------------------------------------------------------
extern "C" void kernel_launch(void* const* d_in, const int* in_sizes, int n_in,
                              void* d_out, int out_size, void* d_ws, size_t ws_size,
                              hipStream_t stream)
{
    const float* feats = (const float*)d_in[0];
    const float* trans = (const float*)d_in[1];

    float* out_f      = (float*)d_out;
    float* path_score = out_f;           // [8192]
    float* best_path  = out_f + BATCH;   // [512 * 8192]

    char* ws = (char*)d_ws;
    uint32_t* bpw  = (uint32_t*)ws;
    int*      ltag = (int*)(ws + 20971520);
    uint64_t* cmap = (uint64_t*)(ws + 21004288);
    uint8_t*  ebuf = (uint8_t*)(ws + 22052864);

    crf_fwd<<<512, 64, 0, stream>>>(feats, trans, path_score, ltag, bpw);
    crf_chunkmap<<<512, 256, 0, stream>>>(bpw, cmap);
    crf_resolve<<<32, 256, 0, stream>>>(cmap, ltag, ebuf);
    crf_emit<<<512, 256, 0, stream>>>(bpw, ebuf, best_path);
}

// Round 4
// 373.369 us; speedup vs baseline: 1.0207x; 1.0207x over previous
//
#include <hip/hip_runtime.h>
#include <stdint.h>

#define NTAG    10
#define SEQ     512
#define BATCH   8192
#define NEG_INF -10000.0f
#define BT10    (BATCH * NTAG)   // 81920: per-timestep dword stride

// ---------------------------------------------------------------------------
// One Viterbi output tag: 10 candidate adds + fused value/index tournament
// (R0's proven structure: strict > takes right, ties keep left = smaller
// index = jnp.argmax first-occurrence). Index selects share the compares
// with value selects -> 38 VALU ops/slot, no separate eq-chain, no max tree.
// ---------------------------------------------------------------------------
__device__ __forceinline__ void slotT(const float r[10], const float tr[10],
                                      float feat, float& fv_out, uint32_t& bp)
{
    const float c0 = r[0] + tr[0], c1 = r[1] + tr[1];
    const float c2 = r[2] + tr[2], c3 = r[3] + tr[3];
    const float c4 = r[4] + tr[4], c5 = r[5] + tr[5];
    const float c6 = r[6] + tr[6], c7 = r[7] + tr[7];
    const float c8 = r[8] + tr[8], c9 = r[9] + tr[9];

    bool t;
    t = c1 > c0;  const float v01 = t ? c1 : c0;  const uint32_t i01 = t ? 1u : 0u;
    t = c3 > c2;  const float v23 = t ? c3 : c2;  const uint32_t i23 = t ? 3u : 2u;
    t = c5 > c4;  const float v45 = t ? c5 : c4;  const uint32_t i45 = t ? 5u : 4u;
    t = c7 > c6;  const float v67 = t ? c7 : c6;  const uint32_t i67 = t ? 7u : 6u;
    t = c9 > c8;  const float v89 = t ? c9 : c8;  const uint32_t i89 = t ? 9u : 8u;
    t = v23 > v01; const float v03 = t ? v23 : v01; const uint32_t i03 = t ? i23 : i01;
    t = v67 > v45; const float v47 = t ? v67 : v45; const uint32_t i47 = t ? i67 : i45;
    t = v47 > v03; const float v07 = t ? v47 : v03; const uint32_t i07 = t ? i47 : i03;
    t = v89 > v07; const float best = t ? v89 : v07; bp = t ? i89 : i07;

    fv_out = best + feat;                 // exact same add as reference
}

// ---------------------------------------------------------------------------
// Forward Viterbi, quad-DPP exchange. 4 lanes per batch (quad lane q owns
// output tags q, q+4, and 8+q for q<2), fv state = 3 regs/lane. Per step the
// 10 fv values are broadcast with 10 mov_dpp quad_perm broadcasts SHARED by
// all three tag slots. Software pipeline is copy-free: fc[j] is reloaded in
// place (next window's address) right after its last use; the final window
// reloads in-bounds dummy data that is never consumed. No LDS, no eq-chain,
// no fn->fc copies. 512 blocks x 64 threads = 512 waves at 1/SIMD.
// fp32 adds/selects bitwise-identical to the reference; ties = first max.
// ---------------------------------------------------------------------------
__global__ __launch_bounds__(64, 1) void crf_fwd(
    const float* __restrict__ feats, const float* __restrict__ trans,
    float* __restrict__ path_score, int* __restrict__ last_tag,
    uint32_t* __restrict__ bpw)
{
    const int lane = threadIdx.x & 63;
    const int q    = lane & 3;             // quad lane = tag group
    const int grp  = lane >> 4;            // unused name guard (see below)
    (void)grp;
    const int gidx = lane >> 2;            // batch within wave (0..15)
    const int b    = blockIdx.x * 16 + gidx;  // 512*16 = 8192 exact

    const int nA = q, nB = q + 4;
    const int rowC = (q < 2) ? (8 + q) : 9;   // lanes 2,3: slot-C dummy

    // transition rows for the owned tags — register-resident
    float trA[10], trB[10], trC[10];
#pragma unroll
    for (int p = 0; p < 10; ++p) {
        trA[p] = trans[nA * NTAG + p];
        trB[p] = trans[nB * NTAG + p];
        trC[p] = trans[rowC * NTAG + p];
    }

    // init: fv[p] = (p==8) ? 0 : -1e4.  A=fv[q], B=fv[q+4], C=fv[8+q]
    float fvA = NEG_INF, fvB = NEG_INF, fvC = (q == 0) ? 0.0f : NEG_INF;

    const float* const fpA0 = feats + b * NTAG + q;   // window-0 base, slot A/B
    const float* const fpC0 = fpA0 + ((q < 2) ? 8 : 0);
    uint32_t* bp_out = bpw + b * NTAG + q;

    // prime window 0
    float fcA[8], fcB[8], fcC[8];
#pragma unroll
    for (int j = 0; j < 8; ++j) {
        fcA[j] = fpA0[j * BT10];
        fcB[j] = fpA0[j * BT10 + 4];
        fcC[j] = fpC0[j * BT10];
    }
    // preload pointers track the NEXT window
    const float* fpAn = fpA0 + 8 * BT10;
    const float* fpCn = fpC0 + 8 * BT10;

    for (int w = 0; w < SEQ / 8; ++w) {
        uint32_t baA = 0, baB = 0, baC = 0;
#pragma unroll
        for (int j = 0; j < 8; ++j) {
            const int Ai = __float_as_int(fvA);
            const int Bi = __float_as_int(fvB);
            const int Ci = __float_as_int(fvC);
            // broadcast all 10 fv values once (quad_perm [s,s,s,s] = s*0x55)
            float r[10];
            r[0] = __int_as_float(__builtin_amdgcn_mov_dpp(Ai, 0x00, 0xF, 0xF, false));
            r[1] = __int_as_float(__builtin_amdgcn_mov_dpp(Ai, 0x55, 0xF, 0xF, false));
            r[2] = __int_as_float(__builtin_amdgcn_mov_dpp(Ai, 0xAA, 0xF, 0xF, false));
            r[3] = __int_as_float(__builtin_amdgcn_mov_dpp(Ai, 0xFF, 0xF, 0xF, false));
            r[4] = __int_as_float(__builtin_amdgcn_mov_dpp(Bi, 0x00, 0xF, 0xF, false));
            r[5] = __int_as_float(__builtin_amdgcn_mov_dpp(Bi, 0x55, 0xF, 0xF, false));
            r[6] = __int_as_float(__builtin_amdgcn_mov_dpp(Bi, 0xAA, 0xF, 0xF, false));
            r[7] = __int_as_float(__builtin_amdgcn_mov_dpp(Bi, 0xFF, 0xF, 0xF, false));
            r[8] = __int_as_float(__builtin_amdgcn_mov_dpp(Ci, 0x00, 0xF, 0xF, false));
            r[9] = __int_as_float(__builtin_amdgcn_mov_dpp(Ci, 0x55, 0xF, 0xF, false));

            uint32_t bpA, bpB, bpC;
            slotT(r, trA, fcA[j], fvA, bpA);
            slotT(r, trB, fcB[j], fvB, bpB);
            slotT(r, trC, fcC[j], fvC, bpC);   // lanes 2,3: dummy, never stored
            baA |= bpA << (4 * j);
            baB |= bpB << (4 * j);
            baC |= bpC << (4 * j);

            // copy-free pipeline: refill this step's feat regs from the NEXT
            // window (final window refills in-bounds dummies, never consumed)
            fcA[j] = fpAn[j * BT10];
            fcB[j] = fpAn[j * BT10 + 4];
            fcC[j] = fpCn[j * BT10];
        }
        bp_out[0] = baA;                       // tags q and q+4: all lanes
        bp_out[4] = baB;
        if (q < 2) bp_out[8] = baC;            // tags 8,9: lanes 0,1 only
        bp_out += BT10;

        // advance preload pointers; clamp so the last window's preloads stay
        // in bounds (their values are never used)
        const bool more = (w < SEQ / 8 - 2);
        fpAn = more ? (fpAn + 8 * BT10) : fpA0;
        fpCn = more ? (fpCn + 8 * BT10) : fpC0;
    }

    // terminal: term[p] = fv[p] + T[STOP][p]; fused tournament, first-max ties
    {
        const int Ai = __float_as_int(fvA);
        const int Bi = __float_as_int(fvB);
        const int Ci = __float_as_int(fvC);
        float r[10];
        r[0] = __int_as_float(__builtin_amdgcn_mov_dpp(Ai, 0x00, 0xF, 0xF, false));
        r[1] = __int_as_float(__builtin_amdgcn_mov_dpp(Ai, 0x55, 0xF, 0xF, false));
        r[2] = __int_as_float(__builtin_amdgcn_mov_dpp(Ai, 0xAA, 0xF, 0xF, false));
        r[3] = __int_as_float(__builtin_amdgcn_mov_dpp(Ai, 0xFF, 0xF, 0xF, false));
        r[4] = __int_as_float(__builtin_amdgcn_mov_dpp(Bi, 0x00, 0xF, 0xF, false));
        r[5] = __int_as_float(__builtin_amdgcn_mov_dpp(Bi, 0x55, 0xF, 0xF, false));
        r[6] = __int_as_float(__builtin_amdgcn_mov_dpp(Bi, 0xAA, 0xF, 0xF, false));
        r[7] = __int_as_float(__builtin_amdgcn_mov_dpp(Bi, 0xFF, 0xF, 0xF, false));
        r[8] = __int_as_float(__builtin_amdgcn_mov_dpp(Ci, 0x00, 0xF, 0xF, false));
        r[9] = __int_as_float(__builtin_amdgcn_mov_dpp(Ci, 0x55, 0xF, 0xF, false));

        float tstop[10];
#pragma unroll
        for (int p = 0; p < 10; ++p) tstop[p] = trans[90 + p];

        float vstar; uint32_t bt;
        slotT(r, tstop, 0.0f, vstar, bt);      // +0.0f: vstar = best + 0 exact?
        // NOTE: best + 0.0f could flip -0.0 -> +0.0; recompute exactly:
        // slotT's fv_out = best + feat. For the terminal we need `best`
        // itself, so redo the final add-free selection here:
        // (cheap: reuse candidates via one more pass)
        float c[10];
#pragma unroll
        for (int p = 0; p < 10; ++p) c[p] = r[p] + tstop[p];
        bool t;
        t = c[1] > c[0]; float v01 = t ? c[1] : c[0]; uint32_t i01 = t ? 1u : 0u;
        t = c[3] > c[2]; float v23 = t ? c[3] : c[2]; uint32_t i23 = t ? 3u : 2u;
        t = c[5] > c[4]; float v45 = t ? c[5] : c[4]; uint32_t i45 = t ? 5u : 4u;
        t = c[7] > c[6]; float v67 = t ? c[7] : c[6]; uint32_t i67 = t ? 7u : 6u;
        t = c[9] > c[8]; float v89 = t ? c[9] : c[8]; uint32_t i89 = t ? 9u : 8u;
        t = v23 > v01;   float v03 = t ? v23 : v01;   uint32_t i03 = t ? i23 : i01;
        t = v67 > v45;   float v47 = t ? v67 : v45;   uint32_t i47 = t ? i67 : i45;
        t = v47 > v03;   float v07 = t ? v47 : v03;   uint32_t i07 = t ? i47 : i03;
        t = v89 > v07;   vstar = t ? v89 : v07;       bt = t ? i89 : i07;

        if (q == 0) { path_score[b] = vstar; last_tag[b] = (int)bt; }
    }
}

// ---------------------------------------------------------------------------
// Pass A: per (chunk c, batch b) compose the 32 per-step backpointer maps in
// registers. Loads coalesced (40 contiguous B/thread) and tag-independent.
// ---------------------------------------------------------------------------
__global__ __launch_bounds__(256) void crf_chunkmap(
    const uint32_t* __restrict__ bpw, uint64_t* __restrict__ cmap)
{
    const int tid = blockIdx.x * 256 + threadIdx.x;   // 131072 = 16 * 8192
    const int b = tid & (BATCH - 1);
    const int c = tid >> 13;

    uint32_t comp[NTAG];
#pragma unroll
    for (int t = 0; t < NTAG; ++t) comp[t] = t;       // identity

    for (int w = 3; w >= 0; --w) {                    // global word c*4+w
        const uint32_t* wp = bpw + (c * 4 + w) * BT10 + b * NTAG;
        const uint64_t q0 = *(const uint64_t*)(wp + 0);
        const uint64_t q1 = *(const uint64_t*)(wp + 2);
        const uint64_t q2 = *(const uint64_t*)(wp + 4);
        const uint64_t q3 = *(const uint64_t*)(wp + 6);
        const uint64_t q4 = *(const uint64_t*)(wp + 8);
        uint32_t wd[10];
        wd[0] = (uint32_t)q0; wd[1] = (uint32_t)(q0 >> 32);
        wd[2] = (uint32_t)q1; wd[3] = (uint32_t)(q1 >> 32);
        wd[4] = (uint32_t)q2; wd[5] = (uint32_t)(q2 >> 32);
        wd[6] = (uint32_t)q3; wd[7] = (uint32_t)(q3 >> 32);
        wd[8] = (uint32_t)q4; wd[9] = (uint32_t)(q4 >> 32);
#pragma unroll
        for (int t = 7; t >= 0; --t) {
            uint32_t lo = 0;
#pragma unroll
            for (int gg = 0; gg < 8; ++gg) lo |= ((wd[gg] >> (4 * t)) & 15u) << (4 * gg);
            const uint32_t hi = ((wd[8] >> (4 * t)) & 15u)
                              | (((wd[9] >> (4 * t)) & 15u) << 4);
            const uint64_t m = ((uint64_t)hi << 32) | lo;
#pragma unroll
            for (int qq = 0; qq < NTAG; ++qq)
                comp[qq] = (uint32_t)((m >> (comp[qq] * 4)) & 15u);
        }
    }
    uint64_t out = 0;
#pragma unroll
    for (int qq = 0; qq < NTAG; ++qq) out |= (uint64_t)comp[qq] << (4 * qq);
    cmap[tid] = out;                                   // tid = c*8192 + b
}

// ---------------------------------------------------------------------------
// Pass B: resolve chunk-entry tags (16 independent loads + register chain).
// ---------------------------------------------------------------------------
__global__ __launch_bounds__(256) void crf_resolve(
    const uint64_t* __restrict__ cmap, const int* __restrict__ last_tag,
    uint8_t* __restrict__ ebuf)
{
    const int b = blockIdx.x * 256 + threadIdx.x;      // 0..8191
    uint64_t cm[16];
#pragma unroll
    for (int c = 0; c < 16; ++c) cm[c] = cmap[c * BATCH + b];
    uint32_t tag = (uint32_t)last_tag[b];
    ebuf[15 * BATCH + b] = (uint8_t)tag;
#pragma unroll
    for (int c = 15; c >= 1; --c) {
        tag = (uint32_t)((cm[c] >> (tag * 4)) & 15u);
        ebuf[(c - 1) * BATCH + b] = (uint8_t)tag;
    }
}

// ---------------------------------------------------------------------------
// Pass C: emit. Re-walk each chunk with the known entry tag; word select by
// tag = cndmask tree (register-space); stores coalesced over b.
// ---------------------------------------------------------------------------
__global__ __launch_bounds__(256) void crf_emit(
    const uint32_t* __restrict__ bpw, const uint8_t* __restrict__ ebuf,
    float* __restrict__ best_path)
{
    const int tid = blockIdx.x * 256 + threadIdx.x;    // 131072
    const int b = tid & (BATCH - 1);
    const int c = tid >> 13;
    uint32_t tag = ebuf[c * BATCH + b];

    for (int w = 3; w >= 0; --w) {
        const uint32_t* wp = bpw + (c * 4 + w) * BT10 + b * NTAG;
        const uint64_t q0 = *(const uint64_t*)(wp + 0);
        const uint64_t q1 = *(const uint64_t*)(wp + 2);
        const uint64_t q2 = *(const uint64_t*)(wp + 4);
        const uint64_t q3 = *(const uint64_t*)(wp + 6);
        const uint64_t q4 = *(const uint64_t*)(wp + 8);
        uint32_t wd[10];
        wd[0] = (uint32_t)q0; wd[1] = (uint32_t)(q0 >> 32);
        wd[2] = (uint32_t)q1; wd[3] = (uint32_t)(q1 >> 32);
        wd[4] = (uint32_t)q2; wd[5] = (uint32_t)(q2 >> 32);
        wd[6] = (uint32_t)q3; wd[7] = (uint32_t)(q3 >> 32);
        wd[8] = (uint32_t)q4; wd[9] = (uint32_t)(q4 >> 32);
#pragma unroll
        for (int t = 7; t >= 0; --t) {
            best_path[(c * 32 + w * 8 + t) * BATCH + b] = (float)tag;  // tag_t
            const uint32_t s0 = (tag & 1) ? wd[1] : wd[0];
            const uint32_t s2 = (tag & 1) ? wd[3] : wd[2];
            const uint32_t s4 = (tag & 1) ? wd[5] : wd[4];
            const uint32_t s6 = (tag & 1) ? wd[7] : wd[6];
            const uint32_t s8 = (tag & 1) ? wd[9] : wd[8];
            const uint32_t t0 = (tag & 2) ? s2 : s0;
            const uint32_t t4 = (tag & 2) ? s6 : s4;
            const uint32_t u0 = (tag & 4) ? t4 : t0;
            const uint32_t sel = (tag & 8) ? s8 : u0;
            tag = (sel >> (4 * t)) & 15u;                              // tag_{t-1}
        }
    }
}

// ---------------------------------------------------------------------------
// d_ws layout (22.2 MB total):
//   [0, 20971520)            bpw  : 64 words x 81920 uint32 (nibble bp)
//   [20971520, +32768)       ltag : 8192 int32
//   [21004288, +1048576)     cmap : 16 x 8192 uint64 (packed chunk maps)
//   [22052864, +131072)      ebuf : 16 x 8192 bytes
// ---------------------------------------------------------------------------
extern "C" void kernel_launch(void* const* d_in, const int* in_sizes, int n_in,
                              void* d_out, int out_size, void* d_ws, size_t ws_size,
                              hipStream_t stream)
{
    const float* feats = (const float*)d_in[0];
    const float* trans = (const float*)d_in[1];

    float* out_f      = (float*)d_out;
    float* path_score = out_f;           // [8192]
    float* best_path  = out_f + BATCH;   // [512 * 8192]

    char* ws = (char*)d_ws;
    uint32_t* bpw  = (uint32_t*)ws;
    int*      ltag = (int*)(ws + 20971520);
    uint64_t* cmap = (uint64_t*)(ws + 21004288);
    uint8_t*  ebuf = (uint8_t*)(ws + 22052864);

    crf_fwd<<<512, 64, 0, stream>>>(feats, trans, path_score, ltag, bpw);
    crf_chunkmap<<<512, 256, 0, stream>>>(bpw, cmap);
    crf_resolve<<<32, 256, 0, stream>>>(cmap, ltag, ebuf);
    crf_emit<<<512, 256, 0, stream>>>(bpw, ebuf, best_path);
}

// Round 5
// 302.246 us; speedup vs baseline: 1.2609x; 1.2353x over previous
//
#include <hip/hip_runtime.h>
#include <stdint.h>

#define NTAG    10
#define SEQ     512
#define BATCH   8192
#define NEG_INF -10000.0f
#define BT10    (BATCH * NTAG)   // 81920: per-timestep dword stride
#define ROWF    12               // floats per LDS fv row (48 B)

// ---------------------------------------------------------------------------
// Forward Viterbi — R0's proven structure (best measured: 147 us) with two
// mechanical fixes:
//  (1) 64-thread blocks (1366 blocks) instead of 256x342: R0's big blocks
//      left 170 of 256 CUs with only 1 wave/SIMD (the critical-path tail);
//      1-wave blocks give every CU 5-6 waves = 1.25-1.5 waves/SIMD uniformly.
//  (2) value max via v_max3 tree (5 ops, 12-cycle chain) + OFF-CHAIN eq-index
//      chain, replacing the 27-op fused tournament whose cmp->cndmask chain
//      sat on the recurrence path. Exact semantics: fp32 max is associative;
//      eq-compare against the exact winner + descending overwrite = lowest
//      index on ties = jnp.argmax.
// Everything else (LDS publish/read, laundering asm, prefetch pipeline,
// nibble bp packing) is byte-identical to the 147-us kernel.
// ---------------------------------------------------------------------------
__global__ __launch_bounds__(64, 1) void crf_fwd(
    const float* __restrict__ feats, const float* __restrict__ trans,
    float* __restrict__ path_score, int* __restrict__ last_tag,
    uint32_t* __restrict__ bpw)
{
    __shared__ float sfv[7 * ROWF];       // 1 wave x 7 rows x 12 floats

    const int lane = threadIdx.x & 63;
    const int g    = lane / 10;           // 0..5 real, 6 = idle lanes
    const int nx   = lane - g * 10;       // 0..9 (idle lanes: 0..3)
    const bool gvalid = (g < 6);

    const int wave_b0 = blockIdx.x * 6;
    if (wave_b0 >= BATCH) return;         // whole-wave early out
    const int b = wave_b0 + (gvalid ? g : 0);
    const bool active = gvalid && (b < BATCH);
    const int bs = (b < BATCH) ? b : (BATCH - 1);

    const int rowbase = g * ROWF;         // g==6 -> scratch row
    int voff = 0;                         // laundered each step

    // transition row T[nx][p] — register-resident for the whole kernel
    float tr[NTAG];
#pragma unroll
    for (int p = 0; p < NTAG; ++p) tr[p] = trans[nx * NTAG + p];

    float fv = (nx == 8) ? 0.0f : NEG_INF;       // START=0, else -1e4
    sfv[rowbase + nx] = fv;

    const float* fp = feats + bs * NTAG + nx;
    uint32_t* bp_out = bpw + bs * NTAG + nx;

    // software pipeline: 8 feats (one bp-word period) prefetched ahead
    float fc[8];
#pragma unroll
    for (int j = 0; j < 8; ++j) fc[j] = fp[j * BT10];
    fp += 8 * BT10;

    for (int w = 0; w < SEQ / 8; ++w) {
        float fn[8];
        if (w < SEQ / 8 - 1) {
#pragma unroll
            for (int j = 0; j < 8; ++j) fn[j] = fp[j * BT10];
            fp += 8 * BT10;
        } else {
#pragma unroll
            for (int j = 0; j < 8; ++j) fn[j] = 0.0f;
        }

        uint32_t bacc = 0;
#pragma unroll
        for (int j = 0; j < 8; ++j) {
            // launder the LDS offset: opaque value -> no load forwarding,
            // no hoisting across the publish-write; emits zero instructions
            __asm__ __volatile__("" : "+v"(voff));
            const float* row = &sfv[rowbase + voff];

            const float4 A  = *(const float4*)(row);
            const float4 Bv = *(const float4*)(row + 4);
            const float2 Cv = *(const float2*)(row + 8);

            const float c0 = A.x  + tr[0];
            const float c1 = A.y  + tr[1];
            const float c2 = A.z  + tr[2];
            const float c3 = A.w  + tr[3];
            const float c4 = Bv.x + tr[4];
            const float c5 = Bv.y + tr[5];
            const float c6 = Bv.z + tr[6];
            const float c7 = Bv.w + tr[7];
            const float c8 = Cv.x + tr[8];
            const float c9 = Cv.y + tr[9];

            // value: max3 tree, 12-cycle chain, exact fp32 max
            const float m0 = fmaxf(fmaxf(c0, c1), c2);
            const float m1 = fmaxf(fmaxf(c3, c4), c5);
            const float m2 = fmaxf(fmaxf(c6, c7), c8);
            const float vstar = fmaxf(fmaxf(m0, m1), fmaxf(m2, c9));

            fv = vstar + fc[j];              // exact same add as reference

            float* roww = &sfv[rowbase + voff];
            roww[nx] = fv;                   // publish for next step ASAP

            // index: off-chain descending eq-overwrite, lowest p wins ties
            uint32_t bp = 9u;
            bp = (c8 == vstar) ? 8u : bp;
            bp = (c7 == vstar) ? 7u : bp;
            bp = (c6 == vstar) ? 6u : bp;
            bp = (c5 == vstar) ? 5u : bp;
            bp = (c4 == vstar) ? 4u : bp;
            bp = (c3 == vstar) ? 3u : bp;
            bp = (c2 == vstar) ? 2u : bp;
            bp = (c1 == vstar) ? 1u : bp;
            bp = (c0 == vstar) ? 0u : bp;
            bacc |= bp << (4 * j);
        }
        if (active) bp_out[0] = bacc;
        bp_out += BT10;
#pragma unroll
        for (int j = 0; j < 8; ++j) fc[j] = fn[j];
    }

    // terminal: term[p] = fv[p] + T[STOP][p]; exact max + first-max index.
    {
        __asm__ __volatile__("" : "+v"(voff));
        const float* row = &sfv[rowbase + voff];
        const float4 A  = *(const float4*)(row);
        const float4 Bv = *(const float4*)(row + 4);
        const float2 Cv = *(const float2*)(row + 8);

        const float c0 = A.x  + trans[90 + 0];
        const float c1 = A.y  + trans[90 + 1];
        const float c2 = A.z  + trans[90 + 2];
        const float c3 = A.w  + trans[90 + 3];
        const float c4 = Bv.x + trans[90 + 4];
        const float c5 = Bv.y + trans[90 + 5];
        const float c6 = Bv.z + trans[90 + 6];
        const float c7 = Bv.w + trans[90 + 7];
        const float c8 = Cv.x + trans[90 + 8];
        const float c9 = Cv.y + trans[90 + 9];

        const float m0 = fmaxf(fmaxf(c0, c1), c2);
        const float m1 = fmaxf(fmaxf(c3, c4), c5);
        const float m2 = fmaxf(fmaxf(c6, c7), c8);
        const float vstar = fmaxf(fmaxf(m0, m1), fmaxf(m2, c9));

        uint32_t bt = 9u;
        bt = (c8 == vstar) ? 8u : bt;
        bt = (c7 == vstar) ? 7u : bt;
        bt = (c6 == vstar) ? 6u : bt;
        bt = (c5 == vstar) ? 5u : bt;
        bt = (c4 == vstar) ? 4u : bt;
        bt = (c3 == vstar) ? 3u : bt;
        bt = (c2 == vstar) ? 2u : bt;
        bt = (c1 == vstar) ? 1u : bt;
        bt = (c0 == vstar) ? 0u : bt;

        if (active && nx == 0) { path_score[b] = vstar; last_tag[b] = (int)bt; }
    }
}

// ---------------------------------------------------------------------------
// Pass A: per (chunk c, batch b) compose the 32 per-step backpointer maps in
// registers. Loads coalesced (40 contiguous B/thread) and tag-independent.
// ---------------------------------------------------------------------------
__global__ __launch_bounds__(256) void crf_chunkmap(
    const uint32_t* __restrict__ bpw, uint64_t* __restrict__ cmap)
{
    const int tid = blockIdx.x * 256 + threadIdx.x;   // 131072 = 16 * 8192
    const int b = tid & (BATCH - 1);
    const int c = tid >> 13;

    uint32_t comp[NTAG];
#pragma unroll
    for (int t = 0; t < NTAG; ++t) comp[t] = t;       // identity

    for (int w = 3; w >= 0; --w) {                    // global word c*4+w
        const uint32_t* wp = bpw + (c * 4 + w) * BT10 + b * NTAG;
        const uint64_t q0 = *(const uint64_t*)(wp + 0);
        const uint64_t q1 = *(const uint64_t*)(wp + 2);
        const uint64_t q2 = *(const uint64_t*)(wp + 4);
        const uint64_t q3 = *(const uint64_t*)(wp + 6);
        const uint64_t q4 = *(const uint64_t*)(wp + 8);
        uint32_t wd[10];
        wd[0] = (uint32_t)q0; wd[1] = (uint32_t)(q0 >> 32);
        wd[2] = (uint32_t)q1; wd[3] = (uint32_t)(q1 >> 32);
        wd[4] = (uint32_t)q2; wd[5] = (uint32_t)(q2 >> 32);
        wd[6] = (uint32_t)q3; wd[7] = (uint32_t)(q3 >> 32);
        wd[8] = (uint32_t)q4; wd[9] = (uint32_t)(q4 >> 32);
#pragma unroll
        for (int t = 7; t >= 0; --t) {
            uint32_t lo = 0;
#pragma unroll
            for (int gg = 0; gg < 8; ++gg) lo |= ((wd[gg] >> (4 * t)) & 15u) << (4 * gg);
            const uint32_t hi = ((wd[8] >> (4 * t)) & 15u)
                              | (((wd[9] >> (4 * t)) & 15u) << 4);
            const uint64_t m = ((uint64_t)hi << 32) | lo;
#pragma unroll
            for (int q = 0; q < NTAG; ++q)
                comp[q] = (uint32_t)((m >> (comp[q] * 4)) & 15u);
        }
    }
    uint64_t out = 0;
#pragma unroll
    for (int q = 0; q < NTAG; ++q) out |= (uint64_t)comp[q] << (4 * q);
    cmap[tid] = out;                                   // tid = c*8192 + b
}

// ---------------------------------------------------------------------------
// Pass B: resolve chunk-entry tags (16 independent loads + register chain).
// ---------------------------------------------------------------------------
__global__ __launch_bounds__(256) void crf_resolve(
    const uint64_t* __restrict__ cmap, const int* __restrict__ last_tag,
    uint8_t* __restrict__ ebuf)
{
    const int b = blockIdx.x * 256 + threadIdx.x;      // 0..8191
    uint64_t cm[16];
#pragma unroll
    for (int c = 0; c < 16; ++c) cm[c] = cmap[c * BATCH + b];
    uint32_t tag = (uint32_t)last_tag[b];
    ebuf[15 * BATCH + b] = (uint8_t)tag;
#pragma unroll
    for (int c = 15; c >= 1; --c) {
        tag = (uint32_t)((cm[c] >> (tag * 4)) & 15u);
        ebuf[(c - 1) * BATCH + b] = (uint8_t)tag;
    }
}

// ---------------------------------------------------------------------------
// Pass C: emit. Re-walk each chunk with the known entry tag; word select by
// tag = cndmask tree (register-space); stores coalesced over b.
// ---------------------------------------------------------------------------
__global__ __launch_bounds__(256) void crf_emit(
    const uint32_t* __restrict__ bpw, const uint8_t* __restrict__ ebuf,
    float* __restrict__ best_path)
{
    const int tid = blockIdx.x * 256 + threadIdx.x;    // 131072
    const int b = tid & (BATCH - 1);
    const int c = tid >> 13;
    uint32_t tag = ebuf[c * BATCH + b];

    for (int w = 3; w >= 0; --w) {
        const uint32_t* wp = bpw + (c * 4 + w) * BT10 + b * NTAG;
        const uint64_t q0 = *(const uint64_t*)(wp + 0);
        const uint64_t q1 = *(const uint64_t*)(wp + 2);
        const uint64_t q2 = *(const uint64_t*)(wp + 4);
        const uint64_t q3 = *(const uint64_t*)(wp + 6);
        const uint64_t q4 = *(const uint64_t*)(wp + 8);
        uint32_t wd[10];
        wd[0] = (uint32_t)q0; wd[1] = (uint32_t)(q0 >> 32);
        wd[2] = (uint32_t)q1; wd[3] = (uint32_t)(q1 >> 32);
        wd[4] = (uint32_t)q2; wd[5] = (uint32_t)(q2 >> 32);
        wd[6] = (uint32_t)q3; wd[7] = (uint32_t)(q3 >> 32);
        wd[8] = (uint32_t)q4; wd[9] = (uint32_t)(q4 >> 32);
#pragma unroll
        for (int t = 7; t >= 0; --t) {
            best_path[(c * 32 + w * 8 + t) * BATCH + b] = (float)tag;  // tag_t
            const uint32_t s0 = (tag & 1) ? wd[1] : wd[0];
            const uint32_t s2 = (tag & 1) ? wd[3] : wd[2];
            const uint32_t s4 = (tag & 1) ? wd[5] : wd[4];
            const uint32_t s6 = (tag & 1) ? wd[7] : wd[6];
            const uint32_t s8 = (tag & 1) ? wd[9] : wd[8];
            const uint32_t t0 = (tag & 2) ? s2 : s0;
            const uint32_t t4 = (tag & 2) ? s6 : s4;
            const uint32_t u0 = (tag & 4) ? t4 : t0;
            const uint32_t sel = (tag & 8) ? s8 : u0;
            tag = (sel >> (4 * t)) & 15u;                              // tag_{t-1}
        }
    }
}

// ---------------------------------------------------------------------------
// d_ws layout (22.2 MB total):
//   [0, 20971520)            bpw  : 64 words x 81920 uint32 (nibble bp)
//   [20971520, +32768)       ltag : 8192 int32
//   [21004288, +1048576)     cmap : 16 x 8192 uint64 (packed chunk maps)
//   [22052864, +131072)      ebuf : 16 x 8192 bytes
// ---------------------------------------------------------------------------
extern "C" void kernel_launch(void* const* d_in, const int* in_sizes, int n_in,
                              void* d_out, int out_size, void* d_ws, size_t ws_size,
                              hipStream_t stream)
{
    const float* feats = (const float*)d_in[0];
    const float* trans = (const float*)d_in[1];

    float* out_f      = (float*)d_out;
    float* path_score = out_f;           // [8192]
    float* best_path  = out_f + BATCH;   // [512 * 8192]

    char* ws = (char*)d_ws;
    uint32_t* bpw  = (uint32_t*)ws;
    int*      ltag = (int*)(ws + 20971520);
    uint64_t* cmap = (uint64_t*)(ws + 21004288);
    uint8_t*  ebuf = (uint8_t*)(ws + 22052864);

    crf_fwd<<<1366, 64, 0, stream>>>(feats, trans, path_score, ltag, bpw);
    crf_chunkmap<<<512, 256, 0, stream>>>(bpw, cmap);
    crf_resolve<<<32, 256, 0, stream>>>(cmap, ltag, ebuf);
    crf_emit<<<512, 256, 0, stream>>>(bpw, ebuf, best_path);
}

// Round 6
// 286.548 us; speedup vs baseline: 1.3300x; 1.0548x over previous
//
#include <hip/hip_runtime.h>
#include <stdint.h>

#define NTAG    10
#define SEQ     512
#define BATCH   8192
#define NEG_INF -10000.0f
#define BT10    (BATCH * NTAG)   // 81920: per-timestep dword stride
#define ROWF    12               // floats per LDS fv row (48 B)

// ---------------------------------------------------------------------------
// Forward Viterbi — R5 structure (117 us) + explicit one-step software
// pipeline of the LDS reads:
//   per step: compute from PRE-LOADED row regs -> publish fv -> relaunder ->
//   ISSUE next-state reads -> (read shadow:) index eq-chain, bacc pack, feat
//   refill. The ~140-180 cyc LDS read latency overlaps the ~25-instr shadow
//   instead of being serially exposed (R5's reads sat at iteration top,
//   pinned after ALL prior-iteration code by the laundering asm).
// Ordering safety: publish-store uses voff_j, reads use voff_{j+1} (both
// opaque, may-alias -> compiler keeps store before loads); same-wave DS ops
// execute in order on the LDS pipe. Copy-free feat pipeline (R4-proven):
// fc[j] refilled from next window right after last use; final window
// refills in-bounds dummies that are never consumed.
// Numerics: same fp32 adds, exact associative fp32 max (max3 tree), eq-
// compare vs exact winner with descending overwrite = first-max ties =
// jnp.argmax. Bitwise-identical to reference.
// ---------------------------------------------------------------------------
__global__ __launch_bounds__(64, 1) void crf_fwd(
    const float* __restrict__ feats, const float* __restrict__ trans,
    float* __restrict__ path_score, int* __restrict__ last_tag,
    uint32_t* __restrict__ bpw)
{
    __shared__ float sfv[7 * ROWF];       // 1 wave x 7 rows x 12 floats

    const int lane = threadIdx.x & 63;
    const int g    = lane / 10;           // 0..5 real, 6 = idle lanes
    const int nx   = lane - g * 10;       // 0..9 (idle lanes: 0..3)
    const bool gvalid = (g < 6);

    const int wave_b0 = blockIdx.x * 6;
    if (wave_b0 >= BATCH) return;         // whole-wave early out
    const int b = wave_b0 + (gvalid ? g : 0);
    const bool active = gvalid && (b < BATCH);
    const int bs = (b < BATCH) ? b : (BATCH - 1);

    const int rowbase = g * ROWF;         // g==6 -> scratch row
    int voff = 0;                         // laundered each step

    // transition row T[nx][p] — register-resident for the whole kernel
    float tr[NTAG];
#pragma unroll
    for (int p = 0; p < NTAG; ++p) tr[p] = trans[nx * NTAG + p];

    float fv = (nx == 8) ? 0.0f : NEG_INF;       // START=0, else -1e4
    sfv[rowbase + nx] = fv;

    // prologue read: state s_0 into row registers
    __asm__ __volatile__("" : "+v"(voff));
    const float* row0 = &sfv[rowbase + voff];
    float4 A  = *(const float4*)(row0);
    float4 Bv = *(const float4*)(row0 + 4);
    float2 Cv = *(const float2*)(row0 + 8);

    const float* const fp0 = feats + bs * NTAG + nx;   // window-0 base
    uint32_t* bp_out = bpw + bs * NTAG + nx;

    // prime feat window 0 (copy-free pipeline; fpn tracks NEXT window)
    float fc[8];
#pragma unroll
    for (int j = 0; j < 8; ++j) fc[j] = fp0[j * BT10];
    const float* fpn = fp0 + 8 * BT10;

    for (int w = 0; w < SEQ / 8; ++w) {
        uint32_t bacc = 0;
#pragma unroll
        for (int j = 0; j < 8; ++j) {
            // ---- compute from pre-loaded row regs (state s_t) ----
            const float c0 = A.x  + tr[0];
            const float c1 = A.y  + tr[1];
            const float c2 = A.z  + tr[2];
            const float c3 = A.w  + tr[3];
            const float c4 = Bv.x + tr[4];
            const float c5 = Bv.y + tr[5];
            const float c6 = Bv.z + tr[6];
            const float c7 = Bv.w + tr[7];
            const float c8 = Cv.x + tr[8];
            const float c9 = Cv.y + tr[9];

            const float m0 = fmaxf(fmaxf(c0, c1), c2);   // v_max3
            const float m1 = fmaxf(fmaxf(c3, c4), c5);
            const float m2 = fmaxf(fmaxf(c6, c7), c8);
            const float vstar = fmaxf(fmaxf(m0, m1), fmaxf(m2, c9));

            fv = vstar + fc[j];              // exact same add as reference

            // ---- publish s_{t+1}, then ISSUE next-state reads ----
            sfv[rowbase + voff + nx] = fv;   // store @ voff_j (opaque)
            __asm__ __volatile__("" : "+v"(voff));   // -> voff_{j+1}
            const float* row = &sfv[rowbase + voff];
            A  = *(const float4*)(row);      // issue now, consume next iter
            Bv = *(const float4*)(row + 4);
            Cv = *(const float2*)(row + 8);

            // ---- read shadow: index recovery + pack + feat refill ----
            uint32_t bp = 9u;
            bp = (c8 == vstar) ? 8u : bp;
            bp = (c7 == vstar) ? 7u : bp;
            bp = (c6 == vstar) ? 6u : bp;
            bp = (c5 == vstar) ? 5u : bp;
            bp = (c4 == vstar) ? 4u : bp;
            bp = (c3 == vstar) ? 3u : bp;
            bp = (c2 == vstar) ? 2u : bp;
            bp = (c1 == vstar) ? 1u : bp;
            bp = (c0 == vstar) ? 0u : bp;
            bacc |= bp << (4 * j);

            fc[j] = fpn[j * BT10];           // refill for next window
        }
        if (active) bp_out[0] = bacc;
        bp_out += BT10;
        // advance refill pointer; clamp so last window's refills stay in
        // bounds (their values are never consumed)
        const bool more = (w < SEQ / 8 - 2);
        fpn = more ? (fpn + 8 * BT10) : fp0;
    }

    // terminal: A,Bv,Cv already hold the final state (read after the last
    // publish). term[p] = fv[p] + T[STOP][p]; exact max + first-max index.
    {
        const float c0 = A.x  + trans[90 + 0];
        const float c1 = A.y  + trans[90 + 1];
        const float c2 = A.z  + trans[90 + 2];
        const float c3 = A.w  + trans[90 + 3];
        const float c4 = Bv.x + trans[90 + 4];
        const float c5 = Bv.y + trans[90 + 5];
        const float c6 = Bv.z + trans[90 + 6];
        const float c7 = Bv.w + trans[90 + 7];
        const float c8 = Cv.x + trans[90 + 8];
        const float c9 = Cv.y + trans[90 + 9];

        const float m0 = fmaxf(fmaxf(c0, c1), c2);
        const float m1 = fmaxf(fmaxf(c3, c4), c5);
        const float m2 = fmaxf(fmaxf(c6, c7), c8);
        const float vstar = fmaxf(fmaxf(m0, m1), fmaxf(m2, c9));

        uint32_t bt = 9u;
        bt = (c8 == vstar) ? 8u : bt;
        bt = (c7 == vstar) ? 7u : bt;
        bt = (c6 == vstar) ? 6u : bt;
        bt = (c5 == vstar) ? 5u : bt;
        bt = (c4 == vstar) ? 4u : bt;
        bt = (c3 == vstar) ? 3u : bt;
        bt = (c2 == vstar) ? 2u : bt;
        bt = (c1 == vstar) ? 1u : bt;
        bt = (c0 == vstar) ? 0u : bt;

        if (active && nx == 0) { path_score[b] = vstar; last_tag[b] = (int)bt; }
    }
}

// ---------------------------------------------------------------------------
// Pass A: per (chunk c, batch b) compose the 32 per-step backpointer maps in
// registers. Loads coalesced (40 contiguous B/thread) and tag-independent.
// ---------------------------------------------------------------------------
__global__ __launch_bounds__(256) void crf_chunkmap(
    const uint32_t* __restrict__ bpw, uint64_t* __restrict__ cmap)
{
    const int tid = blockIdx.x * 256 + threadIdx.x;   // 131072 = 16 * 8192
    const int b = tid & (BATCH - 1);
    const int c = tid >> 13;

    uint32_t comp[NTAG];
#pragma unroll
    for (int t = 0; t < NTAG; ++t) comp[t] = t;       // identity

    for (int w = 3; w >= 0; --w) {                    // global word c*4+w
        const uint32_t* wp = bpw + (c * 4 + w) * BT10 + b * NTAG;
        const uint64_t q0 = *(const uint64_t*)(wp + 0);
        const uint64_t q1 = *(const uint64_t*)(wp + 2);
        const uint64_t q2 = *(const uint64_t*)(wp + 4);
        const uint64_t q3 = *(const uint64_t*)(wp + 6);
        const uint64_t q4 = *(const uint64_t*)(wp + 8);
        uint32_t wd[10];
        wd[0] = (uint32_t)q0; wd[1] = (uint32_t)(q0 >> 32);
        wd[2] = (uint32_t)q1; wd[3] = (uint32_t)(q1 >> 32);
        wd[4] = (uint32_t)q2; wd[5] = (uint32_t)(q2 >> 32);
        wd[6] = (uint32_t)q3; wd[7] = (uint32_t)(q3 >> 32);
        wd[8] = (uint32_t)q4; wd[9] = (uint32_t)(q4 >> 32);
#pragma unroll
        for (int t = 7; t >= 0; --t) {
            uint32_t lo = 0;
#pragma unroll
            for (int gg = 0; gg < 8; ++gg) lo |= ((wd[gg] >> (4 * t)) & 15u) << (4 * gg);
            const uint32_t hi = ((wd[8] >> (4 * t)) & 15u)
                              | (((wd[9] >> (4 * t)) & 15u) << 4);
            const uint64_t m = ((uint64_t)hi << 32) | lo;
#pragma unroll
            for (int q = 0; q < NTAG; ++q)
                comp[q] = (uint32_t)((m >> (comp[q] * 4)) & 15u);
        }
    }
    uint64_t out = 0;
#pragma unroll
    for (int q = 0; q < NTAG; ++q) out |= (uint64_t)comp[q] << (4 * q);
    cmap[tid] = out;                                   // tid = c*8192 + b
}

// ---------------------------------------------------------------------------
// Pass B: resolve chunk-entry tags (16 independent loads + register chain).
// ---------------------------------------------------------------------------
__global__ __launch_bounds__(256) void crf_resolve(
    const uint64_t* __restrict__ cmap, const int* __restrict__ last_tag,
    uint8_t* __restrict__ ebuf)
{
    const int b = blockIdx.x * 256 + threadIdx.x;      // 0..8191
    uint64_t cm[16];
#pragma unroll
    for (int c = 0; c < 16; ++c) cm[c] = cmap[c * BATCH + b];
    uint32_t tag = (uint32_t)last_tag[b];
    ebuf[15 * BATCH + b] = (uint8_t)tag;
#pragma unroll
    for (int c = 15; c >= 1; --c) {
        tag = (uint32_t)((cm[c] >> (tag * 4)) & 15u);
        ebuf[(c - 1) * BATCH + b] = (uint8_t)tag;
    }
}

// ---------------------------------------------------------------------------
// Pass C: emit. Re-walk each chunk with the known entry tag; word select by
// tag = cndmask tree (register-space); stores coalesced over b.
// ---------------------------------------------------------------------------
__global__ __launch_bounds__(256) void crf_emit(
    const uint32_t* __restrict__ bpw, const uint8_t* __restrict__ ebuf,
    float* __restrict__ best_path)
{
    const int tid = blockIdx.x * 256 + threadIdx.x;    // 131072
    const int b = tid & (BATCH - 1);
    const int c = tid >> 13;
    uint32_t tag = ebuf[c * BATCH + b];

    for (int w = 3; w >= 0; --w) {
        const uint32_t* wp = bpw + (c * 4 + w) * BT10 + b * NTAG;
        const uint64_t q0 = *(const uint64_t*)(wp + 0);
        const uint64_t q1 = *(const uint64_t*)(wp + 2);
        const uint64_t q2 = *(const uint64_t*)(wp + 4);
        const uint64_t q3 = *(const uint64_t*)(wp + 6);
        const uint64_t q4 = *(const uint64_t*)(wp + 8);
        uint32_t wd[10];
        wd[0] = (uint32_t)q0; wd[1] = (uint32_t)(q0 >> 32);
        wd[2] = (uint32_t)q1; wd[3] = (uint32_t)(q1 >> 32);
        wd[4] = (uint32_t)q2; wd[5] = (uint32_t)(q2 >> 32);
        wd[6] = (uint32_t)q3; wd[7] = (uint32_t)(q3 >> 32);
        wd[8] = (uint32_t)q4; wd[9] = (uint32_t)(q4 >> 32);
#pragma unroll
        for (int t = 7; t >= 0; --t) {
            best_path[(c * 32 + w * 8 + t) * BATCH + b] = (float)tag;  // tag_t
            const uint32_t s0 = (tag & 1) ? wd[1] : wd[0];
            const uint32_t s2 = (tag & 1) ? wd[3] : wd[2];
            const uint32_t s4 = (tag & 1) ? wd[5] : wd[4];
            const uint32_t s6 = (tag & 1) ? wd[7] : wd[6];
            const uint32_t s8 = (tag & 1) ? wd[9] : wd[8];
            const uint32_t t0 = (tag & 2) ? s2 : s0;
            const uint32_t t4 = (tag & 2) ? s6 : s4;
            const uint32_t u0 = (tag & 4) ? t4 : t0;
            const uint32_t sel = (tag & 8) ? s8 : u0;
            tag = (sel >> (4 * t)) & 15u;                              // tag_{t-1}
        }
    }
}

// ---------------------------------------------------------------------------
// d_ws layout (22.2 MB total):
//   [0, 20971520)            bpw  : 64 words x 81920 uint32 (nibble bp)
//   [20971520, +32768)       ltag : 8192 int32
//   [21004288, +1048576)     cmap : 16 x 8192 uint64 (packed chunk maps)
//   [22052864, +131072)      ebuf : 16 x 8192 bytes
// ---------------------------------------------------------------------------
extern "C" void kernel_launch(void* const* d_in, const int* in_sizes, int n_in,
                              void* d_out, int out_size, void* d_ws, size_t ws_size,
                              hipStream_t stream)
{
    const float* feats = (const float*)d_in[0];
    const float* trans = (const float*)d_in[1];

    float* out_f      = (float*)d_out;
    float* path_score = out_f;           // [8192]
    float* best_path  = out_f + BATCH;   // [512 * 8192]

    char* ws = (char*)d_ws;
    uint32_t* bpw  = (uint32_t*)ws;
    int*      ltag = (int*)(ws + 20971520);
    uint64_t* cmap = (uint64_t*)(ws + 21004288);
    uint8_t*  ebuf = (uint8_t*)(ws + 22052864);

    crf_fwd<<<1366, 64, 0, stream>>>(feats, trans, path_score, ltag, bpw);
    crf_chunkmap<<<512, 256, 0, stream>>>(bpw, cmap);
    crf_resolve<<<32, 256, 0, stream>>>(cmap, ltag, ebuf);
    crf_emit<<<512, 256, 0, stream>>>(bpw, ebuf, best_path);
}